// Round 2
// baseline (1147.911 us; speedup 1.0000x reference)
//
#include <hip/hip_runtime.h>

typedef unsigned char u8;
typedef unsigned int u32;
typedef unsigned long long u64;

#define T_DIM 64
#define B_DIM 8
#define N_DIM 64
#define D_DIM 384
#define H_DIM 8
#define HD 48
#define M_ROWS 32768            // T*B*N = rows of every GEMM
#define CH 196608               // B*N*D = channels per LIF step (also B*T*D)
#define STATS_BLOCKS 256        // m-tiles (128 rows each)

#define BM 128
#define BN 128
#define BK 16
#define KSTEPS (D_DIM / BK)     // 24

// ---------------------------------------------------------------------------
// GEMM (NT) + fused BN-stats partials:
//   C[m,n] = sum_k X[m,k] * W[n,k];  M=32768, N=K=384, f32.
//   part[mtile][n][2] = per-column {sum, sumsq} over the tile's 128 rows (f64).
// 128x128 tile, 256 threads, 8x8 per thread, BK=16, double-buffered LDS,
// one __syncthreads per K-step.
// ---------------------------------------------------------------------------
struct MMBufs { float A[2][BK][BM]; float B[2][BK][BN]; };  // 32 KB
union ShU { MMBufs mm; double red[4096]; };                 // red: dS[16][128], dQ[16][128]

__global__ __launch_bounds__(256) void gemm_bn(const float* __restrict__ X,
                                               const float* __restrict__ W,
                                               float* __restrict__ C,
                                               double* __restrict__ part) {
  __shared__ ShU sh;
  const int tid = threadIdx.x;
  const int bn = blockIdx.x * BN;   // 0..2
  const int by = blockIdx.y;        // 0..255
  const int bm = by * BM;
  const int tx = tid & 15;          // n
  const int ty = tid >> 4;          // m
  const int lrow = tid >> 1;        // 0..127
  const int lk = (tid & 1) * 8;     // 0 or 8

  const float* xp = X + (size_t)(bm + lrow) * D_DIM + lk;
  const float* wp = W + (size_t)(bn + lrow) * D_DIM + lk;

  float4 xa, xb, wa, wb;
  // prologue: tile 0 -> buf 0
  xa = *(const float4*)(xp + 0);
  xb = *(const float4*)(xp + 4);
  wa = *(const float4*)(wp + 0);
  wb = *(const float4*)(wp + 4);
  sh.mm.A[0][lk + 0][lrow] = xa.x; sh.mm.A[0][lk + 1][lrow] = xa.y;
  sh.mm.A[0][lk + 2][lrow] = xa.z; sh.mm.A[0][lk + 3][lrow] = xa.w;
  sh.mm.A[0][lk + 4][lrow] = xb.x; sh.mm.A[0][lk + 5][lrow] = xb.y;
  sh.mm.A[0][lk + 6][lrow] = xb.z; sh.mm.A[0][lk + 7][lrow] = xb.w;
  sh.mm.B[0][lk + 0][lrow] = wa.x; sh.mm.B[0][lk + 1][lrow] = wa.y;
  sh.mm.B[0][lk + 2][lrow] = wa.z; sh.mm.B[0][lk + 3][lrow] = wa.w;
  sh.mm.B[0][lk + 4][lrow] = wb.x; sh.mm.B[0][lk + 5][lrow] = wb.y;
  sh.mm.B[0][lk + 6][lrow] = wb.z; sh.mm.B[0][lk + 7][lrow] = wb.w;
  __syncthreads();

  float acc[8][8] = {};
  int cur = 0;

  for (int ks = 0; ks < KSTEPS; ++ks) {
    // issue next-tile global loads (hidden under compute)
    if (ks < KSTEPS - 1) {
      const float* xq = xp + (ks + 1) * BK;
      const float* wq = wp + (ks + 1) * BK;
      xa = *(const float4*)(xq + 0);
      xb = *(const float4*)(xq + 4);
      wa = *(const float4*)(wq + 0);
      wb = *(const float4*)(wq + 4);
    }
    // compute on buf[cur]
#pragma unroll
    for (int k = 0; k < BK; ++k) {
      float4 a0 = *(const float4*)&sh.mm.A[cur][k][ty * 4];
      float4 a1 = *(const float4*)&sh.mm.A[cur][k][64 + ty * 4];
      float4 b0 = *(const float4*)&sh.mm.B[cur][k][tx * 4];
      float4 b1 = *(const float4*)&sh.mm.B[cur][k][64 + tx * 4];
      float a4[8] = {a0.x, a0.y, a0.z, a0.w, a1.x, a1.y, a1.z, a1.w};
      float b4[8] = {b0.x, b0.y, b0.z, b0.w, b1.x, b1.y, b1.z, b1.w};
#pragma unroll
      for (int i = 0; i < 8; ++i)
#pragma unroll
        for (int j = 0; j < 8; ++j)
          acc[i][j] = fmaf(a4[i], b4[j], acc[i][j]);
    }
    if (ks < KSTEPS - 1) {
      const int nb = cur ^ 1;
      sh.mm.A[nb][lk + 0][lrow] = xa.x; sh.mm.A[nb][lk + 1][lrow] = xa.y;
      sh.mm.A[nb][lk + 2][lrow] = xa.z; sh.mm.A[nb][lk + 3][lrow] = xa.w;
      sh.mm.A[nb][lk + 4][lrow] = xb.x; sh.mm.A[nb][lk + 5][lrow] = xb.y;
      sh.mm.A[nb][lk + 6][lrow] = xb.z; sh.mm.A[nb][lk + 7][lrow] = xb.w;
      sh.mm.B[nb][lk + 0][lrow] = wa.x; sh.mm.B[nb][lk + 1][lrow] = wa.y;
      sh.mm.B[nb][lk + 2][lrow] = wa.z; sh.mm.B[nb][lk + 3][lrow] = wa.w;
      sh.mm.B[nb][lk + 4][lrow] = wb.x; sh.mm.B[nb][lk + 5][lrow] = wb.y;
      sh.mm.B[nb][lk + 6][lrow] = wb.z; sh.mm.B[nb][lk + 7][lrow] = wb.w;
      __syncthreads();
      cur ^= 1;
    }
  }

  // C writes
#pragma unroll
  for (int i = 0; i < 8; ++i) {
    const int row = bm + ((i < 4) ? (ty * 4 + i) : (64 + ty * 4 + i - 4));
    float4 lo = make_float4(acc[i][0], acc[i][1], acc[i][2], acc[i][3]);
    float4 hi = make_float4(acc[i][4], acc[i][5], acc[i][6], acc[i][7]);
    *(float4*)&C[(size_t)row * D_DIM + bn + tx * 4] = lo;
    *(float4*)&C[(size_t)row * D_DIM + bn + 64 + tx * 4] = hi;
  }

  // fused BN partial stats (deterministic fixed-order reduction, f64)
  __syncthreads();  // all LDS compute reads done before reuse
#pragma unroll
  for (int j = 0; j < 8; ++j) {
    const int col = (j < 4) ? (tx * 4 + j) : (64 + tx * 4 + j - 4);
    double s = 0.0, qd = 0.0;
#pragma unroll
    for (int i = 0; i < 8; ++i) {
      const double v = (double)acc[i][j];
      s += v;
      qd += v * v;
    }
    sh.red[ty * 128 + col] = s;
    sh.red[2048 + ty * 128 + col] = qd;
  }
  __syncthreads();
  if (tid < 128) {
    double S = 0.0, Q = 0.0;
#pragma unroll
    for (int r = 0; r < 16; ++r) {
      S += sh.red[r * 128 + tid];
      Q += sh.red[2048 + r * 128 + tid];
    }
    const size_t pidx = ((size_t)by * D_DIM + bn + tid) * 2;
    part[pidx + 0] = S;
    part[pidx + 1] = Q;
  }
}

// ---------------------------------------------------------------------------
// BN stats finalize: reduce 256 tile-partials per channel (fixed order, f64).
// ---------------------------------------------------------------------------
__global__ void bn_stats_final(const double* __restrict__ part,
                               const float* __restrict__ gamma,
                               const float* __restrict__ beta,
                               float* __restrict__ ss) {
  const int c = threadIdx.x;  // 384 threads, 1 block
  double s = 0.0, q = 0.0;
  for (int b = 0; b < STATS_BLOCKS; ++b) {
    s += part[((size_t)b * D_DIM + c) * 2 + 0];
    q += part[((size_t)b * D_DIM + c) * 2 + 1];
  }
  const double n = (double)M_ROWS;
  const double mean = s / n;
  const double var = q / n - mean * mean;
  const double rstd = 1.0 / sqrt(var + 1e-5);
  const double sc = (double)gamma[c] * rstd;
  ss[c * 2 + 0] = (float)sc;
  ss[c * 2 + 1] = (float)((double)beta[c] - mean * sc);
}

// ---------------------------------------------------------------------------
// LIF scan over leading axis (64 steps, stride CH).
// MODE 0: BN affine then LIF, write u8 spikes (branch q/k/v).
// MODE 1: plain LIF, overwrite Y with f32 spikes (attn_lif).
// MODE 2: BN affine then LIF, overwrite Y with f32 spikes (proj_lif).
// ---------------------------------------------------------------------------
template <int MODE>
__global__ __launch_bounds__(256) void lif_kernel(float* Y,
                                                  const float* __restrict__ ss,
                                                  u8* __restrict__ spikes) {
  const int c = blockIdx.x * 256 + threadIdx.x;
  float scale = 1.0f, shift = 0.0f;
  if (MODE != 1) {
    const int dd = c % D_DIM;
    scale = ss[dd * 2 + 0];
    shift = ss[dd * 2 + 1];
  }
  float v = 0.0f;
  for (int t = 0; t < T_DIM; ++t) {
    const size_t idx = (size_t)t * CH + c;
    float xv = Y[idx];
    if (MODE != 1) xv = xv * scale + shift;
    const float hh = v + (xv - v) * 0.5f;
    const float sp = (hh >= 1.0f) ? 1.0f : 0.0f;
    v = (1.0f - sp) * hh;
    if (MODE == 0)
      spikes[idx] = (u8)sp;
    else
      Y[idx] = sp;
  }
}

// ---------------------------------------------------------------------------
// Attention: block = (x,b,h). Spikes are binary -> pack rows to 48-bit masks,
// S[i][j] = popcount(q_i & k_j) * mask(i,j);  Z[i][d] = sum_j S[i][j]*V[j][d].
// z written in permuted layout (i, b, x, h, d).
// ---------------------------------------------------------------------------
__global__ __launch_bounds__(256) void attn_kernel(const u8* __restrict__ qs,
                                                   const u8* __restrict__ ks,
                                                   const u8* __restrict__ vs,
                                                   float* __restrict__ z) {
  const int gid = blockIdx.x;
  const int h = gid & 7;
  const int b = (gid >> 3) & 7;
  const int x = gid >> 6;
  const int tid = threadIdx.x;

  __shared__ u64 qb[64];
  __shared__ u64 kb[64];
  __shared__ float sS[64][65];
  __shared__ u8 sV[64][48];

  if (tid < 64) {
    const int i = tid;  // Q row: qh[x, b, i, h, :]
    const u32* p = (const u32*)(qs + ((size_t)((x * B_DIM + b) * N_DIM + i)) * D_DIM + h * HD);
    u64 bits = 0;
#pragma unroll
    for (int w = 0; w < 12; ++w) {
      u32 u = p[w];
      u32 nib = (u & 1u) | ((u >> 7) & 2u) | ((u >> 14) & 4u) | ((u >> 21) & 8u);
      bits |= (u64)nib << (w * 4);
    }
    qb[i] = bits;
  } else if (tid < 128) {
    const int j = tid - 64;  // K row: kh[j, b, x, h, :]
    const u32* p = (const u32*)(ks + ((size_t)((j * B_DIM + b) * N_DIM + x)) * D_DIM + h * HD);
    u64 bits = 0;
#pragma unroll
    for (int w = 0; w < 12; ++w) {
      u32 u = p[w];
      u32 nib = (u & 1u) | ((u >> 7) & 2u) | ((u >> 14) & 4u) | ((u >> 21) & 8u);
      bits |= (u64)nib << (w * 4);
    }
    kb[j] = bits;
  } else if (tid < 192) {
    const int j = tid - 128;  // V row: vh[j, b, x, h, :]
    const u32* p = (const u32*)(vs + ((size_t)((j * B_DIM + b) * N_DIM + x)) * D_DIM + h * HD);
    u32* dst = (u32*)&sV[j][0];
#pragma unroll
    for (int w = 0; w < 12; ++w) dst[w] = p[w];
  }
  __syncthreads();

  // S phase: 4096 entries, 16 per thread (fixed i per thread)
  {
    const int i = tid >> 2;
    const u64 qi = qb[i];
#pragma unroll
    for (int r = 0; r < 16; ++r) {
      const int j = ((tid & 3) << 4) + r;
      const int cnt = __popcll(qi & kb[j]);
      int ad = i - j;
      if (ad < 0) ad = -ad;
      sS[i][j] = (float)cnt * (1.0f / (float)(1 + ad));
    }
  }
  __syncthreads();

  // Z phase: 3072 outputs, 12 per thread
  const float kScale = 0.05103103630798287f;  // 384^-0.5
#pragma unroll
  for (int r = 0; r < 12; ++r) {
    const int o = (r << 8) + tid;
    const int i = o / HD;
    const int d = o - i * HD;
    float acc = 0.0f;
#pragma unroll
    for (int j = 0; j < 64; ++j)
      acc = fmaf(sS[i][j], (float)sV[j][d], acc);
    z[((size_t)((i * B_DIM + b) * T_DIM + x)) * D_DIM + h * HD + d] = acc * kScale;
  }
}

// ---------------------------------------------------------------------------
extern "C" void kernel_launch(void* const* d_in, const int* in_sizes, int n_in,
                              void* d_out, int out_size, void* d_ws, size_t ws_size,
                              hipStream_t stream) {
  const float* q  = (const float*)d_in[0];
  const float* kv = (const float*)d_in[1];
  const float* Wq = (const float*)d_in[2];
  const float* gq = (const float*)d_in[3];
  const float* bq = (const float*)d_in[4];
  const float* Wk = (const float*)d_in[5];
  const float* gk = (const float*)d_in[6];
  const float* bk = (const float*)d_in[7];
  const float* Wv = (const float*)d_in[8];
  const float* gv = (const float*)d_in[9];
  const float* bv = (const float*)d_in[10];
  const float* Wp = (const float*)d_in[11];
  const float* gp = (const float*)d_in[12];
  const float* bp = (const float*)d_in[13];
  float* out = (float*)d_out;
  char* ws = (char*)d_ws;

  // workspace layout (bytes)
  float* Ybuf  = (float*)(ws + 0);                // 50,331,648  (reused as z)
  u8* qsb      = (u8*)(ws + 50331648ull);         // 12,582,912
  u8* ksb      = (u8*)(ws + 62914560ull);         // 12,582,912
  u8* vsb      = (u8*)(ws + 75497472ull);         // 12,582,912
  double* part = (double*)(ws + 88080384ull);     //  1,572,864
  float* ss    = (float*)(ws + 89653248ull);      //      3,072

  dim3 gg(D_DIM / BN, M_ROWS / BM);  // (3, 256)

  // --- q branch ---
  gemm_bn<<<gg, 256, 0, stream>>>(q, Wq, Ybuf, part);
  bn_stats_final<<<1, D_DIM, 0, stream>>>(part, gq, bq, ss);
  lif_kernel<0><<<CH / 256, 256, 0, stream>>>(Ybuf, ss, qsb);

  // --- k branch ---
  gemm_bn<<<gg, 256, 0, stream>>>(kv, Wk, Ybuf, part);
  bn_stats_final<<<1, D_DIM, 0, stream>>>(part, gk, bk, ss);
  lif_kernel<0><<<CH / 256, 256, 0, stream>>>(Ybuf, ss, ksb);

  // --- v branch ---
  gemm_bn<<<gg, 256, 0, stream>>>(kv, Wv, Ybuf, part);
  bn_stats_final<<<1, D_DIM, 0, stream>>>(part, gv, bv, ss);
  lif_kernel<0><<<CH / 256, 256, 0, stream>>>(Ybuf, ss, vsb);

  // --- attention (writes z into Ybuf in permuted (i,b,x,h,d) layout) ---
  attn_kernel<<<T_DIM * B_DIM * H_DIM, 256, 0, stream>>>(qsb, ksb, vsb, Ybuf);

  // --- attn_lif (in place, f32 spikes) ---
  lif_kernel<1><<<CH / 256, 256, 0, stream>>>(Ybuf, (const float*)nullptr, (u8*)nullptr);

  // --- proj GEMM -> d_out (+ fused stats), then proj_lif in place ---
  gemm_bn<<<gg, 256, 0, stream>>>(Ybuf, Wp, out, part);
  bn_stats_final<<<1, D_DIM, 0, stream>>>(part, gp, bp, ss);
  lif_kernel<2><<<CH / 256, 256, 0, stream>>>(out, ss, (u8*)nullptr);
}

// Round 3
// 810.636 us; speedup vs baseline: 1.4161x; 1.4161x over previous
//
#include <hip/hip_runtime.h>

typedef unsigned char u8;
typedef unsigned int u32;
typedef unsigned long long u64;

#define T_DIM 64
#define B_DIM 8
#define N_DIM 64
#define D_DIM 384
#define H_DIM 8
#define HD 48
#define M_ROWS 32768            // T*B*N = rows of every GEMM
#define CH 196608               // B*N*D = channels per LIF step (also B*T*D)
#define STATS_BLOCKS 256        // m-tiles (128 rows each)

#define BM 128
#define BN 64
#define BK 16
#define KSTEPS (D_DIM / BK)     // 24

// ---------------------------------------------------------------------------
// GEMM (NT) + fused BN-stats partials:
//   C[m,n] = sum_k X[m,k] * W[n,k];  M=32768, N=K=384, f32.
// 128x64 tile, 256 threads, 8x4 micro-tile, BK=16, double-buffered LDS,
// ONE __syncthreads per K-step, register prefetch of next K-chunk.
// LDS strides padded (136 / 68 floats): 16B-aligned for b128, <=2-way banks.
// ---------------------------------------------------------------------------
union ShU {
  struct { float A[2][BK][136]; float B[2][BK][68]; } mm;  // 17408 + 8704 = 26112 B
  double red[16][64][2];                                   // 16384 B (stats)
};

__global__ __launch_bounds__(256, 4) void gemm_bn(const float* __restrict__ X,
                                                  const float* __restrict__ W,
                                                  float* __restrict__ C,
                                                  double* __restrict__ part) {
  __shared__ ShU sh;
  const int tid = threadIdx.x;
  const int bn = blockIdx.x * BN;   // 0..5
  const int by = blockIdx.y;        // 0..255
  const int bm = by * BM;
  const int tx = tid & 15;          // n: 16 threads * 4 cols
  const int ty = tid >> 4;          // m: 16 threads * 8 rows
  const int arow = tid >> 1;        // 0..127
  const int ak = (tid & 1) * 8;     // 0 or 8
  const int brow = tid >> 2;        // 0..63
  const int bk_ = (tid & 3) * 4;    // 0,4,8,12

  const float* xp = X + (size_t)(bm + arow) * D_DIM + ak;
  const float* wp = W + (size_t)(bn + brow) * D_DIM + bk_;

  float4 xa, xb, wa;
  // prologue: K-chunk 0 -> buf 0
  xa = *(const float4*)(xp + 0);
  xb = *(const float4*)(xp + 4);
  wa = *(const float4*)(wp + 0);
  sh.mm.A[0][ak + 0][arow] = xa.x; sh.mm.A[0][ak + 1][arow] = xa.y;
  sh.mm.A[0][ak + 2][arow] = xa.z; sh.mm.A[0][ak + 3][arow] = xa.w;
  sh.mm.A[0][ak + 4][arow] = xb.x; sh.mm.A[0][ak + 5][arow] = xb.y;
  sh.mm.A[0][ak + 6][arow] = xb.z; sh.mm.A[0][ak + 7][arow] = xb.w;
  sh.mm.B[0][bk_ + 0][brow] = wa.x; sh.mm.B[0][bk_ + 1][brow] = wa.y;
  sh.mm.B[0][bk_ + 2][brow] = wa.z; sh.mm.B[0][bk_ + 3][brow] = wa.w;
  __syncthreads();

  float acc[8][4] = {};
  int cur = 0;

  for (int ks = 0; ks < KSTEPS; ++ks) {
    // issue next K-chunk global loads (overlap with compute below)
    if (ks < KSTEPS - 1) {
      const float* xq = xp + (ks + 1) * BK;
      const float* wq = wp + (ks + 1) * BK;
      xa = *(const float4*)(xq + 0);
      xb = *(const float4*)(xq + 4);
      wa = *(const float4*)(wq + 0);
    }
#pragma unroll
    for (int k = 0; k < BK; ++k) {
      float4 a0 = *(const float4*)&sh.mm.A[cur][k][ty * 8];
      float4 a1 = *(const float4*)&sh.mm.A[cur][k][ty * 8 + 4];
      float4 b0 = *(const float4*)&sh.mm.B[cur][k][tx * 4];
      float av[8] = {a0.x, a0.y, a0.z, a0.w, a1.x, a1.y, a1.z, a1.w};
      float bv[4] = {b0.x, b0.y, b0.z, b0.w};
#pragma unroll
      for (int i = 0; i < 8; ++i)
#pragma unroll
        for (int j = 0; j < 4; ++j)
          acc[i][j] = fmaf(av[i], bv[j], acc[i][j]);
    }
    if (ks < KSTEPS - 1) {
      const int nb = cur ^ 1;
      sh.mm.A[nb][ak + 0][arow] = xa.x; sh.mm.A[nb][ak + 1][arow] = xa.y;
      sh.mm.A[nb][ak + 2][arow] = xa.z; sh.mm.A[nb][ak + 3][arow] = xa.w;
      sh.mm.A[nb][ak + 4][arow] = xb.x; sh.mm.A[nb][ak + 5][arow] = xb.y;
      sh.mm.A[nb][ak + 6][arow] = xb.z; sh.mm.A[nb][ak + 7][arow] = xb.w;
      sh.mm.B[nb][bk_ + 0][brow] = wa.x; sh.mm.B[nb][bk_ + 1][brow] = wa.y;
      sh.mm.B[nb][bk_ + 2][brow] = wa.z; sh.mm.B[nb][bk_ + 3][brow] = wa.w;
      __syncthreads();
      cur = nb;
    }
  }

  // C writes: 8 rows x float4
#pragma unroll
  for (int i = 0; i < 8; ++i) {
    float4 o = make_float4(acc[i][0], acc[i][1], acc[i][2], acc[i][3]);
    *(float4*)&C[(size_t)(bm + ty * 8 + i) * D_DIM + bn + tx * 4] = o;
  }

  // fused BN partial stats (deterministic fixed order, f64)
  __syncthreads();  // all compute reads of LDS done before union reuse
#pragma unroll
  for (int j = 0; j < 4; ++j) {
    const int col = tx * 4 + j;
    double s = 0.0, qd = 0.0;
#pragma unroll
    for (int i = 0; i < 8; ++i) {
      const double v = (double)acc[i][j];
      s += v;
      qd += v * v;
    }
    sh.red[ty][col][0] = s;
    sh.red[ty][col][1] = qd;
  }
  __syncthreads();
  if (tid < 64) {
    double S = 0.0, Q = 0.0;
#pragma unroll
    for (int r = 0; r < 16; ++r) {
      S += sh.red[r][tid][0];
      Q += sh.red[r][tid][1];
    }
    const size_t pidx = ((size_t)by * D_DIM + bn + tid) * 2;
    part[pidx + 0] = S;
    part[pidx + 1] = Q;
  }
}

// ---------------------------------------------------------------------------
// BN stats finalize: reduce 256 tile-partials per channel (fixed order, f64).
// 6 blocks x 64 threads.
// ---------------------------------------------------------------------------
__global__ void bn_stats_final(const double* __restrict__ part,
                               const float* __restrict__ gamma,
                               const float* __restrict__ beta,
                               float* __restrict__ ss) {
  const int c = blockIdx.x * 64 + threadIdx.x;
  double s = 0.0, q = 0.0;
  for (int b = 0; b < STATS_BLOCKS; ++b) {
    s += part[((size_t)b * D_DIM + c) * 2 + 0];
    q += part[((size_t)b * D_DIM + c) * 2 + 1];
  }
  const double n = (double)M_ROWS;
  const double mean = s / n;
  const double var = q / n - mean * mean;
  const double rstd = 1.0 / sqrt(var + 1e-5);
  const double sc = (double)gamma[c] * rstd;
  ss[c * 2 + 0] = (float)sc;
  ss[c * 2 + 1] = (float)((double)beta[c] - mean * sc);
}

// ---------------------------------------------------------------------------
// LIF scan over leading axis (64 steps, stride CH), chunk-8 load prefetch.
// MODE 0: BN affine then LIF, write u8 spikes (branch q/k/v).
// MODE 2: BN affine then LIF, overwrite Y with f32 spikes (proj_lif).
// ---------------------------------------------------------------------------
template <int MODE>
__global__ __launch_bounds__(256) void lif_kernel(float* Y,
                                                  const float* __restrict__ ss,
                                                  u8* __restrict__ spikes) {
  const int c = blockIdx.x * 256 + threadIdx.x;
  const int dd = c % D_DIM;
  const float scale = ss[dd * 2 + 0];
  const float shift = ss[dd * 2 + 1];
  float v = 0.0f;
  for (int t0 = 0; t0 < T_DIM; t0 += 8) {
    float xs[8];
#pragma unroll
    for (int u = 0; u < 8; ++u) xs[u] = Y[(size_t)(t0 + u) * CH + c];
#pragma unroll
    for (int u = 0; u < 8; ++u) {
      const float xv = xs[u] * scale + shift;
      const float hh = v + (xv - v) * 0.5f;
      const float sp = (hh >= 1.0f) ? 1.0f : 0.0f;
      v = (1.0f - sp) * hh;
      if (MODE == 0)
        spikes[(size_t)(t0 + u) * CH + c] = (u8)sp;
      else
        Y[(size_t)(t0 + u) * CH + c] = sp;
    }
  }
}

// ---------------------------------------------------------------------------
// Attention + fused attn_lif. Block = (x,b,h). Spikes binary -> 48-bit masks,
// S[i][j] = popcount(q_i & k_j)*mask(i,j); Z[i][d] = sum_j S[i][j]*V[j][d].
// Then LIF over i (the z-reshape leading axis) per (d)-channel, writing f32
// spikes directly in permuted (i,b,x,h,d) layout.
// ---------------------------------------------------------------------------
__global__ __launch_bounds__(256) void attn_kernel(const u8* __restrict__ qs,
                                                   const u8* __restrict__ ks,
                                                   const u8* __restrict__ vs,
                                                   float* __restrict__ z) {
  const int gid = blockIdx.x;
  const int h = gid & 7;
  const int b = (gid >> 3) & 7;
  const int x = gid >> 6;
  const int tid = threadIdx.x;

  __shared__ u64 qb[64];
  __shared__ u64 kb[64];
  __shared__ float sS[64][65];
  __shared__ u8 sV[64][48];
  __shared__ float zb[64][49];

  if (tid < 64) {
    const int i = tid;  // Q row: qh[x, b, i, h, :]
    const u32* p = (const u32*)(qs + ((size_t)((x * B_DIM + b) * N_DIM + i)) * D_DIM + h * HD);
    u64 bits = 0;
#pragma unroll
    for (int w = 0; w < 12; ++w) {
      u32 u = p[w];
      u32 nib = (u & 1u) | ((u >> 7) & 2u) | ((u >> 14) & 4u) | ((u >> 21) & 8u);
      bits |= (u64)nib << (w * 4);
    }
    qb[i] = bits;
  } else if (tid < 128) {
    const int j = tid - 64;  // K row: kh[j, b, x, h, :]
    const u32* p = (const u32*)(ks + ((size_t)((j * B_DIM + b) * N_DIM + x)) * D_DIM + h * HD);
    u64 bits = 0;
#pragma unroll
    for (int w = 0; w < 12; ++w) {
      u32 u = p[w];
      u32 nib = (u & 1u) | ((u >> 7) & 2u) | ((u >> 14) & 4u) | ((u >> 21) & 8u);
      bits |= (u64)nib << (w * 4);
    }
    kb[j] = bits;
  } else if (tid < 192) {
    const int j = tid - 128;  // V row: vh[j, b, x, h, :]
    const u32* p = (const u32*)(vs + ((size_t)((j * B_DIM + b) * N_DIM + x)) * D_DIM + h * HD);
    u32* dst = (u32*)&sV[j][0];
#pragma unroll
    for (int w = 0; w < 12; ++w) dst[w] = p[w];
  }
  __syncthreads();

  // S phase
  {
    const int i = tid >> 2;
    const u64 qi = qb[i];
#pragma unroll
    for (int r = 0; r < 16; ++r) {
      const int j = ((tid & 3) << 4) + r;
      const int cnt = __popcll(qi & kb[j]);
      int ad = i - j;
      if (ad < 0) ad = -ad;
      sS[i][j] = (float)cnt * (1.0f / (float)(1 + ad));
    }
  }
  __syncthreads();

  // Z phase -> LDS
  const float kScale = 0.05103103630798287f;  // 384^-0.5
#pragma unroll
  for (int r = 0; r < 12; ++r) {
    const int o = (r << 8) + tid;
    const int i = o / HD;
    const int d = o - i * HD;
    float acc = 0.0f;
#pragma unroll
    for (int j = 0; j < 64; ++j)
      acc = fmaf(sS[i][j], (float)sV[j][d], acc);
    zb[i][d] = acc * kScale;
  }
  __syncthreads();

  // fused attn_lif: scan over i per d-channel, write f32 spikes
  if (tid < HD) {
    const int d = tid;
    float v = 0.0f;
    for (int i = 0; i < 64; ++i) {
      const float hh = v + (zb[i][d] - v) * 0.5f;
      const float sp = (hh >= 1.0f) ? 1.0f : 0.0f;
      v = (1.0f - sp) * hh;
      z[((size_t)((i * B_DIM + b) * T_DIM + x)) * D_DIM + h * HD + d] = sp;
    }
  }
}

// ---------------------------------------------------------------------------
extern "C" void kernel_launch(void* const* d_in, const int* in_sizes, int n_in,
                              void* d_out, int out_size, void* d_ws, size_t ws_size,
                              hipStream_t stream) {
  const float* q  = (const float*)d_in[0];
  const float* kv = (const float*)d_in[1];
  const float* Wq = (const float*)d_in[2];
  const float* gq = (const float*)d_in[3];
  const float* bq = (const float*)d_in[4];
  const float* Wk = (const float*)d_in[5];
  const float* gk = (const float*)d_in[6];
  const float* bk = (const float*)d_in[7];
  const float* Wv = (const float*)d_in[8];
  const float* gv = (const float*)d_in[9];
  const float* bv = (const float*)d_in[10];
  const float* Wp = (const float*)d_in[11];
  const float* gp = (const float*)d_in[12];
  const float* bp = (const float*)d_in[13];
  float* out = (float*)d_out;
  char* ws = (char*)d_ws;

  // workspace layout (bytes)
  float* Ybuf  = (float*)(ws + 0);                // 50,331,648  (Y, then z-spikes)
  u8* qsb      = (u8*)(ws + 50331648ull);         // 12,582,912
  u8* ksb      = (u8*)(ws + 62914560ull);         // 12,582,912
  u8* vsb      = (u8*)(ws + 75497472ull);         // 12,582,912
  double* part = (double*)(ws + 88080384ull);     //  1,572,864
  float* ss    = (float*)(ws + 89653248ull);      //      3,072

  dim3 gg(D_DIM / BN, M_ROWS / BM);  // (6, 256)

  // --- q branch ---
  gemm_bn<<<gg, 256, 0, stream>>>(q, Wq, Ybuf, part);
  bn_stats_final<<<6, 64, 0, stream>>>(part, gq, bq, ss);
  lif_kernel<0><<<CH / 256, 256, 0, stream>>>(Ybuf, ss, qsb);

  // --- k branch ---
  gemm_bn<<<gg, 256, 0, stream>>>(kv, Wk, Ybuf, part);
  bn_stats_final<<<6, 64, 0, stream>>>(part, gk, bk, ss);
  lif_kernel<0><<<CH / 256, 256, 0, stream>>>(Ybuf, ss, ksb);

  // --- v branch ---
  gemm_bn<<<gg, 256, 0, stream>>>(kv, Wv, Ybuf, part);
  bn_stats_final<<<6, 64, 0, stream>>>(part, gv, bv, ss);
  lif_kernel<0><<<CH / 256, 256, 0, stream>>>(Ybuf, ss, vsb);

  // --- attention + fused attn_lif (writes f32 spikes into Ybuf) ---
  attn_kernel<<<T_DIM * B_DIM * H_DIM, 256, 0, stream>>>(qsb, ksb, vsb, Ybuf);

  // --- proj GEMM -> d_out (+ fused stats), then proj_lif in place ---
  gemm_bn<<<gg, 256, 0, stream>>>(Ybuf, Wp, out, part);
  bn_stats_final<<<6, 64, 0, stream>>>(part, gp, bp, ss);
  lif_kernel<2><<<CH / 256, 256, 0, stream>>>(out, ss, (u8*)nullptr);
}